// Round 10
// baseline (143.892 us; speedup 1.0000x reference)
//
#include <hip/hip_runtime.h>
#include <hip/hip_bf16.h>
#include <cstdint>
#include <cmath>

// Problem constants
#define LSEQ 512
#define EDIM 64
#define NBIG 8192   // 16*8*64 total n dimension

typedef __attribute__((ext_vector_type(8))) short short8;
typedef __attribute__((ext_vector_type(8))) unsigned short ushort8v;
typedef __attribute__((ext_vector_type(4))) float f32x4;

__device__ __forceinline__ unsigned short f2bf(float f) {
    union { float f; unsigned int u; } x; x.f = f;
    unsigned int r = x.u + 0x7FFFu + ((x.u >> 16) & 1u);
    return (unsigned short)(r >> 16);
}

__device__ __forceinline__ void async_copy16(void* lds, const void* g) {
    auto g1 = (const __attribute__((address_space(1))) void*)g;
    auto l3 = (__attribute__((address_space(3))) void*)lds;
    __builtin_amdgcn_global_load_lds(g1, l3, 16, 0, 0);
}

// Swizzled 16-elem store: within the 64-elem chunk at cbase, 8-elem granule g
// lands at physical granule p = g ^ (row & 7).
__device__ __forceinline__ void store16_swz(unsigned short* rowptr, int cbase,
                                            int q, int row,
                                            const unsigned short* o) {
    int x = row & 7, x1 = x >> 1, x0 = x & 1;
    unsigned short* dst = rowptr + cbase + ((q ^ x1) << 4);
    ushort8v lo = *(const ushort8v*)o;
    ushort8v hi = *(const ushort8v*)(o + 8);
    if (x0) { *(ushort8v*)dst = hi; *(ushort8v*)(dst + 8) = lo; }
    else    { *(ushort8v*)dst = lo; *(ushort8v*)(dst + 8) = hi; }
}

// ---------------------------------------------------------------------------
struct PrepS {
    float Ls[70 * 65];
    float red[16][64];
    float wcoef[448];
};
struct GemmS {
    unsigned short As[2][128 * 64];
    unsigned short Bs[2][64 * 64];
};
union SmemU {
    PrepS p;
    GemmS g;
};

// ---------------------------------------------------------------------------
// Manual grid barrier. SAFE because grid=512 blocks x 256 thr with 48KB LDS and
// __launch_bounds__(256,2) guarantees 2 blocks/CU x 256 CUs all co-resident.
// Counter is zeroed by a prior init kernel each call (deterministic replays).
__device__ __forceinline__ void grid_barrier(unsigned int* cnt, unsigned int target) {
    __syncthreads();
    if (threadIdx.x == 0) {
        __threadfence();                      // release: flush writes device-wide
        atomicAdd(cnt, 1u);                   // device-scope, coherent across XCDs
        while (atomicAdd(cnt, 0u) < target) { __builtin_amdgcn_s_sleep(8); }
        __threadfence();                      // acquire: invalidate stale caches
    }
    __syncthreads();
}

// ---------------------------------------------------------------------------
// Prep unit (round-6 prep body):
//  id 0..1023   : (b,h,jt) V-tile -> Vpp (bf16, swizzled) + conv->inv
//  id 1024..1087: U tile -> Ut (transposed), Ub (straight), swizzled
__device__ __forceinline__ void prep_unit(
        int id, int t, PrepS& sm,
        const float* __restrict__ vals, const float* __restrict__ U,
        const float* __restrict__ cw, const float* __restrict__ cb,
        const float* __restrict__ S,
        unsigned short* __restrict__ Vpp, unsigned short* __restrict__ Ut,
        unsigned short* __restrict__ Ub, float* __restrict__ inv) {
    if (id < 1024) {
        int b = id >> 6, h = (id >> 3) & 7, jt = id & 7;
        int j0 = jt * 64;
        for (int idx = t; idx < 448; idx += 256) sm.wcoef[idx] = cw[idx];
        const float* base = vals + (size_t)b * 262144 + h * 64;
        #pragma unroll
        for (int i = 0; i < 5; ++i) {
            int idx = i * 256 + t;
            if (idx < 1120) {
                int row = idx >> 4, c4 = (idx & 15) * 4;
                int grow = j0 + row - 3;
                grow = grow < 0 ? 0 : (grow > 511 ? 511 : grow);
                float4 v = *(const float4*)(base + (size_t)grow * 512 + c4);
                float* d = &sm.Ls[row * 65 + c4];
                d[0] = v.x; d[1] = v.y; d[2] = v.z; d[3] = v.w;
            }
        }
        __syncthreads();

        // transpose -> Vpp (bf16, swizzled)
        {
            int e = t & 63, q = t >> 6;
            unsigned short o[16];
            #pragma unroll
            for (int jj = 0; jj < 16; ++jj)
                o[jj] = f2bf(sm.Ls[(3 + q * 16 + jj) * 65 + e]);
            int n = b * 512 + h * 64 + e;
            store16_swz(Vpp + (size_t)n * 512, j0, q, n, o);
        }

        // conv partials
        {
            int lg = t & 15, q16 = t >> 4;
            int l0 = lg * 4, e0 = q16 * 4;
            float rv[10][4];
            #pragma unroll
            for (int r = 0; r < 10; ++r)
                #pragma unroll
                for (int je = 0; je < 4; ++je)
                    rv[r][je] = sm.Ls[(l0 + r) * 65 + e0 + je];
            float a4[4] = {0.f, 0.f, 0.f, 0.f};
            #pragma unroll
            for (int kk = 0; kk < 7; ++kk) {
                #pragma unroll
                for (int je = 0; je < 4; ++je) {
                    float w = sm.wcoef[(e0 + je) * 7 + kk];
                    #pragma unroll
                    for (int dl = 0; dl < 4; ++dl)
                        a4[dl] += rv[dl + kk][je] * w;
                }
            }
            #pragma unroll
            for (int dl = 0; dl < 4; ++dl) sm.red[q16][l0 + dl] = a4[dl];
        }
        __syncthreads();
        if (t < 64) {
            float y = cb[0];
            #pragma unroll
            for (int g = 0; g < 16; ++g) y += sm.red[g][t];
            float lam = (y > 0.f) ? (1.f + y) : expf(y);   // 1 + elu(y)
            inv[(size_t)(b * 8 + h) * 512 + j0 + t] = 1.f / (1.f + lam * S[j0 + t]);
        }
        __syncthreads();   // protect Ls before next unit reuses it
    } else {
        int id2 = id - 1024;
        int j0 = (id2 >> 3) * 64, m0 = (id2 & 7) * 64;
        int r = t >> 2, q = t & 3;
        int c16 = q * 16;
        float v[16];
        const float* src = U + (size_t)(j0 + r) * 512 + m0 + c16;
        #pragma unroll
        for (int k = 0; k < 16; k += 4) {
            float4 vv = *(const float4*)(src + k);
            v[k] = vv.x; v[k+1] = vv.y; v[k+2] = vv.z; v[k+3] = vv.w;
        }
        {
            unsigned short o[16];
            #pragma unroll
            for (int k = 0; k < 16; ++k) o[k] = f2bf(v[k]);
            store16_swz(Ub + (size_t)(j0 + r) * 512, m0, q, j0 + r, o);
        }
        #pragma unroll
        for (int k = 0; k < 16; ++k) sm.Ls[r * 65 + c16 + k] = v[k];
        __syncthreads();
        {
            unsigned short o[16];
            #pragma unroll
            for (int k = 0; k < 16; ++k) o[k] = f2bf(sm.Ls[(c16 + k) * 65 + r]);
            store16_swz(Ut + (size_t)(m0 + r) * 512, j0, q, m0 + r, o);
        }
        __syncthreads();
    }
}

// ---------------------------------------------------------------------------
// GEMM body (round-6 config verbatim): C[512][8192] = A[512x512] * B[n][k],
// tile 128m x 64n, BK=64, double-buffered, 512 blocks (2/CU independent).
// EPI=1: Tpp[n][m] = bf16(C*inv) swizzled.  EPI=2: out fp32.
template<int EPI>
__device__ __forceinline__ void gemm_body(
        int bid, int t, GemmS& sm,
        const unsigned short* __restrict__ A,
        const unsigned short* __restrict__ B,
        const float* __restrict__ inv,
        unsigned short* __restrict__ Tout,
        float* __restrict__ Out) {
    bid = (bid & 7) * 64 + (bid >> 3);           // XCD chunked swizzle (512 % 8 == 0)
    int mt = bid & 3, nt = bid >> 2;
    int m0 = mt * 128, n0 = nt * 64;
    int lane = t & 63, wave = t >> 6;
    int wm = wave >> 1, wn = wave & 1;
    int l15 = lane & 15, l4 = lane >> 4;

    f32x4 acc[4][2] = {};

    const unsigned short* Ab = A + (size_t)(m0 + (t >> 3)) * 512 + (t & 7) * 8;
    const unsigned short* Bb = B + (size_t)(n0 + (t >> 3)) * 512 + (t & 7) * 8;

    auto STAGE = [&](int buf, int kk) {
        int ko = kk * 64;
        unsigned short* ap = &sm.As[buf][t * 8];
        unsigned short* bp = &sm.Bs[buf][t * 8];
        async_copy16(ap,        Ab + ko);
        async_copy16(ap + 2048, Ab + (size_t)32 * 512 + ko);
        async_copy16(ap + 4096, Ab + (size_t)64 * 512 + ko);
        async_copy16(ap + 6144, Ab + (size_t)96 * 512 + ko);
        async_copy16(bp,        Bb + ko);
        async_copy16(bp + 2048, Bb + (size_t)32 * 512 + ko);
    };
    auto COMPUTE = [&](int buf) {
        #pragma unroll
        for (int k2 = 0; k2 < 2; ++k2) {
            short8 a[4], bf[2];
            #pragma unroll
            for (int i = 0; i < 4; ++i) {
                int row = wm * 64 + i * 16 + l15;
                a[i] = *(const short8*)&sm.As[buf][row * 64 + (((k2 * 4 + l4) ^ (row & 7)) << 3)];
            }
            #pragma unroll
            for (int j = 0; j < 2; ++j) {
                int row = wn * 32 + j * 16 + l15;
                bf[j] = *(const short8*)&sm.Bs[buf][row * 64 + (((k2 * 4 + l4) ^ (row & 7)) << 3)];
            }
            #pragma unroll
            for (int i = 0; i < 4; ++i)
                #pragma unroll
                for (int j = 0; j < 2; ++j)
                    acc[i][j] = __builtin_amdgcn_mfma_f32_16x16x32_bf16(a[i], bf[j], acc[i][j], 0, 0, 0);
        }
    };

    STAGE(0, 0);
    __syncthreads();
    int cur = 0;
    #pragma unroll
    for (int kk = 0; kk < 7; ++kk) {
        STAGE(cur ^ 1, kk + 1);
        COMPUTE(cur);
        __syncthreads();
        cur ^= 1;
    }
    COMPUTE(cur);

    #pragma unroll
    for (int i = 0; i < 4; ++i) {
        int mb = m0 + wm * 64 + i * 16 + l4 * 4;
        if (EPI == 1) {
            float4 s = *(const float4*)&inv[(size_t)nt * 512 + mb];
            #pragma unroll
            for (int j = 0; j < 2; ++j) {
                int n = n0 + wn * 32 + j * 16 + l15;
                f32x4 v = acc[i][j];
                ushort4 pack;
                pack.x = f2bf(v[0] * s.x);
                pack.y = f2bf(v[1] * s.y);
                pack.z = f2bf(v[2] * s.z);
                pack.w = f2bf(v[3] * s.w);
                int e = mb & 63;
                int pos = (mb & ~63) + ((((e >> 3) ^ (n & 7)) << 3) | (e & 7));
                *(ushort4*)&Tout[(size_t)n * 512 + pos] = pack;
            }
        } else {
            #pragma unroll
            for (int j = 0; j < 2; ++j) {
                int n = n0 + wn * 32 + j * 16 + l15;
                int b = n >> 9, hd = n & 511;
                f32x4 v = acc[i][j];
                float* o = Out + (size_t)b * 262144 + (size_t)mb * 512 + hd;
                o[0] = v[0]; o[512] = v[1]; o[1024] = v[2]; o[1536] = v[3];
            }
        }
    }
}

// ---------------------------------------------------------------------------
__global__ void init_kernel(unsigned int* cnt) { *cnt = 0u; }

// Fused: prep (grid-stride) -> barrier -> GEMM1 -> barrier -> GEMM2
__global__ __launch_bounds__(256, 2) void fused_kernel(
        const float* __restrict__ vals, const float* __restrict__ U,
        const float* __restrict__ cw, const float* __restrict__ cb,
        const float* __restrict__ S,
        unsigned short* __restrict__ Vpp, unsigned short* __restrict__ Ut,
        unsigned short* __restrict__ Ub, float* __restrict__ inv,
        unsigned short* __restrict__ Tpp, float* __restrict__ Out,
        unsigned int* cnt) {
    __shared__ __align__(16) SmemU smem;
    int t = threadIdx.x;

    for (int u = blockIdx.x; u < 1088; u += gridDim.x)
        prep_unit(u, t, smem.p, vals, U, cw, cb, S, Vpp, Ut, Ub, inv);

    grid_barrier(cnt, 512);
    gemm_body<1>(blockIdx.x, t, smem.g, Ut, Vpp, inv, Tpp, nullptr);
    grid_barrier(cnt, 1024);
    gemm_body<2>(blockIdx.x, t, smem.g, Ub, Tpp, nullptr, nullptr, Out);
}

// ---------------------------------------------------------------------------
extern "C" void kernel_launch(void* const* d_in, const int* in_sizes, int n_in,
                              void* d_out, int out_size, void* d_ws, size_t ws_size,
                              hipStream_t stream) {
    const float* vals = (const float*)d_in[0];
    const float* cw   = (const float*)d_in[1];
    const float* cb   = (const float*)d_in[2];
    const float* U    = (const float*)d_in[3];
    const float* S    = (const float*)d_in[4];
    float* out = (float*)d_out;

    const size_t off_Ut  = 0;              // 512KB
    const size_t off_Ub  = 524288;         // 512KB
    const size_t off_V   = 1048576;        // 8MB
    const size_t off_T   = 9437184;        // 8MB
    const size_t off_inv = 17825792;       // 256KB
    const size_t off_cnt = 18087936;       // 4B barrier counter
    const size_t ws_need = 18088000;
    if (ws_size < ws_need) return;

    char* ws = (char*)d_ws;
    unsigned short* Ut  = (unsigned short*)(ws + off_Ut);
    unsigned short* Ub  = (unsigned short*)(ws + off_Ub);
    unsigned short* Vpp = (unsigned short*)(ws + off_V);
    unsigned short* Tpp = (unsigned short*)(ws + off_T);
    float*          inv = (float*)(ws + off_inv);
    unsigned int*   cnt = (unsigned int*)(ws + off_cnt);

    init_kernel<<<1, 1, 0, stream>>>(cnt);
    fused_kernel<<<512, 256, 0, stream>>>(vals, U, cw, cb, S,
                                          Vpp, Ut, Ub, inv, Tpp, out, cnt);
}

// Round 11
// 122.522 us; speedup vs baseline: 1.1744x; 1.1744x over previous
//
#include <hip/hip_runtime.h>
#include <hip/hip_bf16.h>
#include <cstdint>
#include <cmath>

// Problem constants
#define LSEQ 512
#define EDIM 64
#define NBIG 8192   // 16*8*64 total n dimension

typedef __attribute__((ext_vector_type(8))) short short8;
typedef __attribute__((ext_vector_type(8))) unsigned short ushort8v;
typedef __attribute__((ext_vector_type(4))) float f32x4;

__device__ __forceinline__ unsigned short f2bf(float f) {
    union { float f; unsigned int u; } x; x.f = f;
    unsigned int r = x.u + 0x7FFFu + ((x.u >> 16) & 1u);
    return (unsigned short)(r >> 16);
}

__device__ __forceinline__ void async_copy16(void* lds, const void* g) {
    auto g1 = (const __attribute__((address_space(1))) void*)g;
    auto l3 = (__attribute__((address_space(3))) void*)lds;
    __builtin_amdgcn_global_load_lds(g1, l3, 16, 0, 0);
}

// Swizzled 16-elem store: within the 64-elem chunk at cbase, 8-elem granule g
// lands at physical granule p = g ^ (row & 7).
__device__ __forceinline__ void store16_swz(unsigned short* rowptr, int cbase,
                                            int q, int row,
                                            const unsigned short* o) {
    int x = row & 7, x1 = x >> 1, x0 = x & 1;
    unsigned short* dst = rowptr + cbase + ((q ^ x1) << 4);
    ushort8v lo = *(const ushort8v*)o;
    ushort8v hi = *(const ushort8v*)(o + 8);
    if (x0) { *(ushort8v*)dst = hi; *(ushort8v*)(dst + 8) = lo; }
    else    { *(ushort8v*)dst = lo; *(ushort8v*)(dst + 8) = hi; }
}

// ---------------------------------------------------------------------------
struct PrepS {
    float Ls[70 * 65];
    float red[16][64];
    float wcoef[448];
};
struct GemmS {
    unsigned short As[2][128 * 64];
    unsigned short Bs[2][64 * 64];
};
union SmemU {
    PrepS p;
    GemmS g;
};

// ---------------------------------------------------------------------------
// Flag helpers. Layout: flags[i*16] (64B-padded slots).
//   slot 0        : uflag   (target 64)
//   slot 1+bh     : vflag   (bh in 0..127, target 8)
//   slot 129+nt   : tflag   (nt in 0..127, target 4)
// signal: caller must be immediately after a __syncthreads() (vmcnt drained).
__device__ __forceinline__ void signal_flag(unsigned int* f) {
    if (threadIdx.x == 0) {
        __threadfence();          // writeback XCD L2 -> device-visible
        atomicAdd(f, 1u);         // single RMW per producer (no spin RMWs)
    }
}
__device__ __forceinline__ void spin_ge(unsigned int* f, unsigned int tgt) {
    while (__hip_atomic_load(f, __ATOMIC_RELAXED, __HIP_MEMORY_SCOPE_AGENT) < tgt)
        __builtin_amdgcn_s_sleep(2);
}

// ---------------------------------------------------------------------------
// Prep unit (round-6 body):
//  id 0..1023   : (b,h,jt) V-tile -> Vpp (bf16, swizzled) + conv->inv
//  id 1024..1087: U tile -> Ut (transposed), Ub (straight), swizzled
__device__ __forceinline__ void prep_unit(
        int id, int t, PrepS& sm,
        const float* __restrict__ vals, const float* __restrict__ U,
        const float* __restrict__ cw, const float* __restrict__ cb,
        const float* __restrict__ S,
        unsigned short* __restrict__ Vpp, unsigned short* __restrict__ Ut,
        unsigned short* __restrict__ Ub, float* __restrict__ inv) {
    if (id < 1024) {
        int b = id >> 6, h = (id >> 3) & 7, jt = id & 7;
        int j0 = jt * 64;
        for (int idx = t; idx < 448; idx += 256) sm.wcoef[idx] = cw[idx];
        const float* base = vals + (size_t)b * 262144 + h * 64;
        #pragma unroll
        for (int i = 0; i < 5; ++i) {
            int idx = i * 256 + t;
            if (idx < 1120) {
                int row = idx >> 4, c4 = (idx & 15) * 4;
                int grow = j0 + row - 3;
                grow = grow < 0 ? 0 : (grow > 511 ? 511 : grow);
                float4 v = *(const float4*)(base + (size_t)grow * 512 + c4);
                float* d = &sm.Ls[row * 65 + c4];
                d[0] = v.x; d[1] = v.y; d[2] = v.z; d[3] = v.w;
            }
        }
        __syncthreads();

        // transpose -> Vpp (bf16, swizzled)
        {
            int e = t & 63, q = t >> 6;
            unsigned short o[16];
            #pragma unroll
            for (int jj = 0; jj < 16; ++jj)
                o[jj] = f2bf(sm.Ls[(3 + q * 16 + jj) * 65 + e]);
            int n = b * 512 + h * 64 + e;
            store16_swz(Vpp + (size_t)n * 512, j0, q, n, o);
        }

        // conv partials
        {
            int lg = t & 15, q16 = t >> 4;
            int l0 = lg * 4, e0 = q16 * 4;
            float rv[10][4];
            #pragma unroll
            for (int r = 0; r < 10; ++r)
                #pragma unroll
                for (int je = 0; je < 4; ++je)
                    rv[r][je] = sm.Ls[(l0 + r) * 65 + e0 + je];
            float a4[4] = {0.f, 0.f, 0.f, 0.f};
            #pragma unroll
            for (int kk = 0; kk < 7; ++kk) {
                #pragma unroll
                for (int je = 0; je < 4; ++je) {
                    float w = sm.wcoef[(e0 + je) * 7 + kk];
                    #pragma unroll
                    for (int dl = 0; dl < 4; ++dl)
                        a4[dl] += rv[dl + kk][je] * w;
                }
            }
            #pragma unroll
            for (int dl = 0; dl < 4; ++dl) sm.red[q16][l0 + dl] = a4[dl];
        }
        __syncthreads();
        if (t < 64) {
            float y = cb[0];
            #pragma unroll
            for (int g = 0; g < 16; ++g) y += sm.red[g][t];
            float lam = (y > 0.f) ? (1.f + y) : expf(y);   // 1 + elu(y)
            inv[(size_t)(b * 8 + h) * 512 + j0 + t] = 1.f / (1.f + lam * S[j0 + t]);
        }
        __syncthreads();   // drains all stores (vmcnt) before signal
    } else {
        int id2 = id - 1024;
        int j0 = (id2 >> 3) * 64, m0 = (id2 & 7) * 64;
        int r = t >> 2, q = t & 3;
        int c16 = q * 16;
        float v[16];
        const float* src = U + (size_t)(j0 + r) * 512 + m0 + c16;
        #pragma unroll
        for (int k = 0; k < 16; k += 4) {
            float4 vv = *(const float4*)(src + k);
            v[k] = vv.x; v[k+1] = vv.y; v[k+2] = vv.z; v[k+3] = vv.w;
        }
        {
            unsigned short o[16];
            #pragma unroll
            for (int k = 0; k < 16; ++k) o[k] = f2bf(v[k]);
            store16_swz(Ub + (size_t)(j0 + r) * 512, m0, q, j0 + r, o);
        }
        #pragma unroll
        for (int k = 0; k < 16; ++k) sm.Ls[r * 65 + c16 + k] = v[k];
        __syncthreads();
        {
            unsigned short o[16];
            #pragma unroll
            for (int k = 0; k < 16; ++k) o[k] = f2bf(sm.Ls[(c16 + k) * 65 + r]);
            store16_swz(Ut + (size_t)(m0 + r) * 512, j0, q, m0 + r, o);
        }
        __syncthreads();   // drains stores before signal
    }
}

// ---------------------------------------------------------------------------
// GEMM body (round-6 config; sbid pre-swizzled): C[512][8192] = A * B[n][k],
// tile 128m x 64n, BK=64, double-buffered.
// EPI=1: Tpp[n][m] = bf16(C*inv) swizzled.  EPI=2: out fp32.
template<int EPI>
__device__ __forceinline__ void gemm_body(
        int sbid, int t, GemmS& sm,
        const unsigned short* __restrict__ A,
        const unsigned short* __restrict__ B,
        const float* __restrict__ inv,
        unsigned short* __restrict__ Tout,
        float* __restrict__ Out) {
    int mt = sbid & 3, nt = sbid >> 2;
    int m0 = mt * 128, n0 = nt * 64;
    int lane = t & 63, wave = t >> 6;
    int wm = wave >> 1, wn = wave & 1;
    int l15 = lane & 15, l4 = lane >> 4;

    f32x4 acc[4][2] = {};

    const unsigned short* Ab = A + (size_t)(m0 + (t >> 3)) * 512 + (t & 7) * 8;
    const unsigned short* Bb = B + (size_t)(n0 + (t >> 3)) * 512 + (t & 7) * 8;

    auto STAGE = [&](int buf, int kk) {
        int ko = kk * 64;
        unsigned short* ap = &sm.As[buf][t * 8];
        unsigned short* bp = &sm.Bs[buf][t * 8];
        async_copy16(ap,        Ab + ko);
        async_copy16(ap + 2048, Ab + (size_t)32 * 512 + ko);
        async_copy16(ap + 4096, Ab + (size_t)64 * 512 + ko);
        async_copy16(ap + 6144, Ab + (size_t)96 * 512 + ko);
        async_copy16(bp,        Bb + ko);
        async_copy16(bp + 2048, Bb + (size_t)32 * 512 + ko);
    };
    auto COMPUTE = [&](int buf) {
        #pragma unroll
        for (int k2 = 0; k2 < 2; ++k2) {
            short8 a[4], bf[2];
            #pragma unroll
            for (int i = 0; i < 4; ++i) {
                int row = wm * 64 + i * 16 + l15;
                a[i] = *(const short8*)&sm.As[buf][row * 64 + (((k2 * 4 + l4) ^ (row & 7)) << 3)];
            }
            #pragma unroll
            for (int j = 0; j < 2; ++j) {
                int row = wn * 32 + j * 16 + l15;
                bf[j] = *(const short8*)&sm.Bs[buf][row * 64 + (((k2 * 4 + l4) ^ (row & 7)) << 3)];
            }
            #pragma unroll
            for (int i = 0; i < 4; ++i)
                #pragma unroll
                for (int j = 0; j < 2; ++j)
                    acc[i][j] = __builtin_amdgcn_mfma_f32_16x16x32_bf16(a[i], bf[j], acc[i][j], 0, 0, 0);
        }
    };

    STAGE(0, 0);
    __syncthreads();
    int cur = 0;
    #pragma unroll
    for (int kk = 0; kk < 7; ++kk) {
        STAGE(cur ^ 1, kk + 1);
        COMPUTE(cur);
        __syncthreads();
        cur ^= 1;
    }
    COMPUTE(cur);

    #pragma unroll
    for (int i = 0; i < 4; ++i) {
        int mb = m0 + wm * 64 + i * 16 + l4 * 4;
        if (EPI == 1) {
            float4 s = *(const float4*)&inv[(size_t)nt * 512 + mb];
            #pragma unroll
            for (int j = 0; j < 2; ++j) {
                int n = n0 + wn * 32 + j * 16 + l15;
                f32x4 v = acc[i][j];
                ushort4 pack;
                pack.x = f2bf(v[0] * s.x);
                pack.y = f2bf(v[1] * s.y);
                pack.z = f2bf(v[2] * s.z);
                pack.w = f2bf(v[3] * s.w);
                int e = mb & 63;
                int pos = (mb & ~63) + ((((e >> 3) ^ (n & 7)) << 3) | (e & 7));
                *(ushort4*)&Tout[(size_t)n * 512 + pos] = pack;
            }
        } else {
            #pragma unroll
            for (int j = 0; j < 2; ++j) {
                int n = n0 + wn * 32 + j * 16 + l15;
                int b = n >> 9, hd = n & 511;
                f32x4 v = acc[i][j];
                float* o = Out + (size_t)b * 262144 + (size_t)mb * 512 + hd;
                o[0] = v[0]; o[512] = v[1]; o[1024] = v[2]; o[1536] = v[3];
            }
        }
    }
}

// ---------------------------------------------------------------------------
__global__ void init_kernel(unsigned int* flags) {
    for (int i = threadIdx.x; i < 257 * 16; i += 256) flags[i] = 0u;
}

// Fused with fine-grained flags: prep units -> GEMM1(nt) -> GEMM2(nt).
// 512 blocks x 256 thr, 48KB LDS, launch_bounds(256,2): all co-resident
// (empirically proven by round-10's completing grid barrier).
__global__ __launch_bounds__(256, 2) void fused_kernel(
        const float* __restrict__ vals, const float* __restrict__ U,
        const float* __restrict__ cw, const float* __restrict__ cb,
        const float* __restrict__ S,
        unsigned short* __restrict__ Vpp, unsigned short* __restrict__ Ut,
        unsigned short* __restrict__ Ub, float* __restrict__ inv,
        unsigned short* __restrict__ Tpp, float* __restrict__ Out,
        unsigned int* flags) {
    __shared__ __align__(16) SmemU smem;
    int t = threadIdx.x;
    int bid = blockIdx.x;

    // ---- prep phase (U-units first so uflag fills early) ----
    if (bid < 64) {
        prep_unit(1024 + bid, t, smem.p, vals, U, cw, cb, S, Vpp, Ut, Ub, inv);
        signal_flag(flags);                              // uflag
    }
    prep_unit(bid, t, smem.p, vals, U, cw, cb, S, Vpp, Ut, Ub, inv);
    signal_flag(flags + (size_t)(1 + (bid >> 3)) * 16);          // vflag[bh]
    prep_unit(bid + 512, t, smem.p, vals, U, cw, cb, S, Vpp, Ut, Ub, inv);
    signal_flag(flags + (size_t)(1 + ((bid + 512) >> 3)) * 16);  // vflag[bh]

    // ---- GEMM1: wait for Ut complete + this n-range's Vpp producers ----
    int sbid = (bid & 7) * 64 + (bid >> 3);   // XCD chunked swizzle
    int nt = sbid >> 2;
    __syncthreads();
    if (t == 0) {
        spin_ge(flags, 64);                          // uflag == 64
        spin_ge(flags + (size_t)(1 + nt) * 16, 8);   // vflag[nt] == 8
        __threadfence();                             // invalidate stale L2
    }
    __syncthreads();
    gemm_body<1>(sbid, t, smem.g, Ut, Vpp, inv, Tpp, nullptr);
    __syncthreads();                                  // drain Tpp stores
    signal_flag(flags + (size_t)(129 + nt) * 16);     // tflag[nt]

    // ---- GEMM2: wait for this n-range's 4 Tpp producers ----
    __syncthreads();
    if (t == 0) {
        spin_ge(flags + (size_t)(129 + nt) * 16, 4);
        __threadfence();
    }
    __syncthreads();
    gemm_body<2>(sbid, t, smem.g, Ub, Tpp, nullptr, nullptr, Out);
}

// ---------------------------------------------------------------------------
extern "C" void kernel_launch(void* const* d_in, const int* in_sizes, int n_in,
                              void* d_out, int out_size, void* d_ws, size_t ws_size,
                              hipStream_t stream) {
    const float* vals = (const float*)d_in[0];
    const float* cw   = (const float*)d_in[1];
    const float* cb   = (const float*)d_in[2];
    const float* U    = (const float*)d_in[3];
    const float* S    = (const float*)d_in[4];
    float* out = (float*)d_out;

    const size_t off_Ut   = 0;              // 512KB
    const size_t off_Ub   = 524288;         // 512KB
    const size_t off_V    = 1048576;        // 8MB
    const size_t off_T    = 9437184;        // 8MB
    const size_t off_inv  = 17825792;       // 256KB
    const size_t off_flag = 18087936;       // 257 * 64B = 16448B
    const size_t ws_need  = 18104384;
    if (ws_size < ws_need) return;

    char* ws = (char*)d_ws;
    unsigned short* Ut   = (unsigned short*)(ws + off_Ut);
    unsigned short* Ub   = (unsigned short*)(ws + off_Ub);
    unsigned short* Vpp  = (unsigned short*)(ws + off_V);
    unsigned short* Tpp  = (unsigned short*)(ws + off_T);
    float*          inv  = (float*)(ws + off_inv);
    unsigned int*   flags = (unsigned int*)(ws + off_flag);

    init_kernel<<<1, 256, 0, stream>>>(flags);
    fused_kernel<<<512, 256, 0, stream>>>(vals, U, cw, cb, S,
                                          Vpp, Ut, Ub, inv, Tpp, out, flags);
}

// Round 12
// 42.602 us; speedup vs baseline: 3.3776x; 2.8760x over previous
//
#include <hip/hip_runtime.h>
#include <hip/hip_bf16.h>
#include <cstdint>
#include <cmath>

// Problem constants
#define LSEQ 512
#define EDIM 64
#define NBIG 8192   // 16*8*64 total n dimension

typedef __attribute__((ext_vector_type(8))) short short8;
typedef __attribute__((ext_vector_type(8))) unsigned short ushort8v;
typedef __attribute__((ext_vector_type(4))) float f32x4;

__device__ __forceinline__ unsigned short f2bf(float f) {
    union { float f; unsigned int u; } x; x.f = f;
    unsigned int r = x.u + 0x7FFFu + ((x.u >> 16) & 1u);
    return (unsigned short)(r >> 16);
}

// Swizzled 16-elem store: within the 64-elem chunk at cbase, 8-elem granule g
// lands at physical granule p = g ^ (row & 7).
__device__ __forceinline__ void store16_swz(unsigned short* rowptr, int cbase,
                                            int q, int row,
                                            const unsigned short* o) {
    int x = row & 7, x1 = x >> 1, x0 = x & 1;
    unsigned short* dst = rowptr + cbase + ((q ^ x1) << 4);
    ushort8v lo = *(const ushort8v*)o;
    ushort8v hi = *(const ushort8v*)(o + 8);
    if (x0) { *(ushort8v*)dst = hi; *(ushort8v*)(dst + 8) = lo; }
    else    { *(ushort8v*)dst = lo; *(ushort8v*)(dst + 8) = hi; }
}

// ---------------------------------------------------------------------------
// Fused prep (round-6 version, unchanged):
//  blocks 0..1023  : (b,h,jt) — values tile -> Vpp bf16 swizzled [n][j] + conv->inv
//  blocks 1024..1087: U tiles — Ut[m][j]=U[j][m], Ub[i][m]=U[i][m], swizzled
__global__ __launch_bounds__(256) void prep_kernel(
        const float* __restrict__ vals, const float* __restrict__ U,
        const float* __restrict__ cw, const float* __restrict__ cb,
        const float* __restrict__ S,
        unsigned short* __restrict__ Vpp, unsigned short* __restrict__ Ut,
        unsigned short* __restrict__ Ub, float* __restrict__ inv) {
    __shared__ float Ls[70 * 65];        // stride 65 (odd) -> conflict-free both axes
    __shared__ float red[16][64];
    __shared__ float wcoef[448];
    int id = blockIdx.x;
    int t = threadIdx.x;

    if (id < 1024) {
        int b = id >> 6, h = (id >> 3) & 7, jt = id & 7;
        int j0 = jt * 64;
        for (int idx = t; idx < 448; idx += 256) wcoef[idx] = cw[idx];
        const float* base = vals + (size_t)b * 262144 + h * 64;
        #pragma unroll
        for (int i = 0; i < 5; ++i) {
            int idx = i * 256 + t;
            if (idx < 1120) {
                int row = idx >> 4, c4 = (idx & 15) * 4;
                int grow = j0 + row - 3;
                grow = grow < 0 ? 0 : (grow > 511 ? 511 : grow);
                float4 v = *(const float4*)(base + (size_t)grow * 512 + c4);
                float* d = &Ls[row * 65 + c4];
                d[0] = v.x; d[1] = v.y; d[2] = v.z; d[3] = v.w;
            }
        }
        __syncthreads();

        // transpose -> Vpp (bf16, swizzled)
        {
            int e = t & 63, q = t >> 6;
            unsigned short o[16];
            #pragma unroll
            for (int jj = 0; jj < 16; ++jj)
                o[jj] = f2bf(Ls[(3 + q * 16 + jj) * 65 + e]);
            int n = b * 512 + h * 64 + e;
            store16_swz(Vpp + (size_t)n * 512, j0, q, n, o);
        }

        // conv partials
        {
            int lg = t & 15, q16 = t >> 4;
            int l0 = lg * 4, e0 = q16 * 4;
            float rv[10][4];
            #pragma unroll
            for (int r = 0; r < 10; ++r)
                #pragma unroll
                for (int je = 0; je < 4; ++je)
                    rv[r][je] = Ls[(l0 + r) * 65 + e0 + je];
            float a4[4] = {0.f, 0.f, 0.f, 0.f};
            #pragma unroll
            for (int kk = 0; kk < 7; ++kk) {
                #pragma unroll
                for (int je = 0; je < 4; ++je) {
                    float w = wcoef[(e0 + je) * 7 + kk];
                    #pragma unroll
                    for (int dl = 0; dl < 4; ++dl)
                        a4[dl] += rv[dl + kk][je] * w;
                }
            }
            #pragma unroll
            for (int dl = 0; dl < 4; ++dl) red[q16][l0 + dl] = a4[dl];
        }
        __syncthreads();
        if (t < 64) {
            float y = cb[0];
            #pragma unroll
            for (int g = 0; g < 16; ++g) y += red[g][t];
            float lam = (y > 0.f) ? (1.f + y) : expf(y);   // 1 + elu(y)
            inv[(size_t)(b * 8 + h) * 512 + j0 + t] = 1.f / (1.f + lam * S[j0 + t]);
        }
    } else {
        int id2 = id - 1024;
        int j0 = (id2 >> 3) * 64, m0 = (id2 & 7) * 64;
        int r = t >> 2, q = t & 3;
        int c16 = q * 16;
        float v[16];
        const float* src = U + (size_t)(j0 + r) * 512 + m0 + c16;
        #pragma unroll
        for (int k = 0; k < 16; k += 4) {
            float4 vv = *(const float4*)(src + k);
            v[k] = vv.x; v[k+1] = vv.y; v[k+2] = vv.z; v[k+3] = vv.w;
        }
        {
            unsigned short o[16];
            #pragma unroll
            for (int k = 0; k < 16; ++k) o[k] = f2bf(v[k]);
            store16_swz(Ub + (size_t)(j0 + r) * 512, m0, q, j0 + r, o);
        }
        #pragma unroll
        for (int k = 0; k < 16; ++k) Ls[r * 65 + c16 + k] = v[k];
        __syncthreads();
        {
            unsigned short o[16];
            #pragma unroll
            for (int k = 0; k < 16; ++k) o[k] = f2bf(Ls[(c16 + k) * 65 + r]);
            store16_swz(Ut + (size_t)(m0 + r) * 512, j0, q, m0 + r, o);
        }
    }
}

// ---------------------------------------------------------------------------
// GEMM round 12: NO LDS, NO BARRIERS. Both operands are granule-swizzled in
// global memory; each lane loads its MFMA fragments directly (16B/lane; the
// XOR makes each 4-lane (l4) group a contiguous 64B segment -> coalesced L2).
// Tile 128m x 64n, 4 waves (64m x 32n each), K fully unrolled (8 x BK64).
// EPI=1: Tpp[n][m] = bf16(C*inv), swizzled.  EPI=2: out fp32.
template<int EPI>
__launch_bounds__(256, 2)
__global__ void gemm_kernel(const unsigned short* __restrict__ A,
                            const unsigned short* __restrict__ B,
                            const float* __restrict__ inv,
                            unsigned short* __restrict__ Tout,
                            float* __restrict__ Out) {
    int bid = blockIdx.x;
    bid = (bid & 7) * 64 + (bid >> 3);           // XCD chunked swizzle (512 % 8 == 0)
    int mt = bid & 3, nt = bid >> 2;
    int m0 = mt * 128, n0 = nt * 64;
    int t = threadIdx.x, lane = t & 63, wave = t >> 6;
    int wm = wave >> 1, wn = wave & 1;
    int l15 = lane & 15, l4 = lane >> 4;

    f32x4 acc[4][2] = {};

    // Per-lane loop-invariant row bases and XOR keys.
    const unsigned short* abase[4];
    int ax[4];
    #pragma unroll
    for (int i = 0; i < 4; ++i) {
        int row = m0 + wm * 64 + i * 16 + l15;
        abase[i] = A + (size_t)row * 512;
        ax[i] = row & 7;
    }
    const unsigned short* bbase[2];
    int bx[2];
    #pragma unroll
    for (int j = 0; j < 2; ++j) {
        int row = n0 + wn * 32 + j * 16 + l15;
        bbase[j] = B + (size_t)row * 512;
        bx[j] = row & 7;
    }

    #pragma unroll
    for (int kk = 0; kk < 8; ++kk) {
        #pragma unroll
        for (int k2 = 0; k2 < 2; ++k2) {
            int g = k2 * 4 + l4;
            short8 a[4], bfr[2];
            #pragma unroll
            for (int i = 0; i < 4; ++i)
                a[i] = *(const short8*)(abase[i] + kk * 64 + ((g ^ ax[i]) << 3));
            #pragma unroll
            for (int j = 0; j < 2; ++j)
                bfr[j] = *(const short8*)(bbase[j] + kk * 64 + ((g ^ bx[j]) << 3));
            #pragma unroll
            for (int i = 0; i < 4; ++i)
                #pragma unroll
                for (int j = 0; j < 2; ++j)
                    acc[i][j] = __builtin_amdgcn_mfma_f32_16x16x32_bf16(a[i], bfr[j], acc[i][j], 0, 0, 0);
        }
    }

    #pragma unroll
    for (int i = 0; i < 4; ++i) {
        int mb = m0 + wm * 64 + i * 16 + l4 * 4;
        if (EPI == 1) {
            float4 s = *(const float4*)&inv[(size_t)nt * 512 + mb];
            #pragma unroll
            for (int j = 0; j < 2; ++j) {
                int n = n0 + wn * 32 + j * 16 + l15;
                f32x4 v = acc[i][j];
                ushort4 pack;
                pack.x = f2bf(v[0] * s.x);
                pack.y = f2bf(v[1] * s.y);
                pack.z = f2bf(v[2] * s.z);
                pack.w = f2bf(v[3] * s.w);
                int e = mb & 63;
                int pos = (mb & ~63) + ((((e >> 3) ^ (n & 7)) << 3) | (e & 7));
                *(ushort4*)&Tout[(size_t)n * 512 + pos] = pack;
            }
        } else {
            #pragma unroll
            for (int j = 0; j < 2; ++j) {
                int n = n0 + wn * 32 + j * 16 + l15;
                int b = n >> 9, hd = n & 511;
                f32x4 v = acc[i][j];
                float* o = Out + (size_t)b * 262144 + (size_t)mb * 512 + hd;
                o[0] = v[0]; o[512] = v[1]; o[1024] = v[2]; o[1536] = v[3];
            }
        }
    }
}

// ---------------------------------------------------------------------------
extern "C" void kernel_launch(void* const* d_in, const int* in_sizes, int n_in,
                              void* d_out, int out_size, void* d_ws, size_t ws_size,
                              hipStream_t stream) {
    const float* vals = (const float*)d_in[0];
    const float* cw   = (const float*)d_in[1];
    const float* cb   = (const float*)d_in[2];
    const float* U    = (const float*)d_in[3];
    const float* S    = (const float*)d_in[4];
    float* out = (float*)d_out;

    const size_t off_Ut  = 0;              // 512KB
    const size_t off_Ub  = 524288;         // 512KB
    const size_t off_V   = 1048576;        // 8MB
    const size_t off_T   = 9437184;        // 8MB
    const size_t off_inv = 17825792;       // 256KB
    const size_t ws_need = 18087936;
    if (ws_size < ws_need) return;

    char* ws = (char*)d_ws;
    unsigned short* Ut  = (unsigned short*)(ws + off_Ut);
    unsigned short* Ub  = (unsigned short*)(ws + off_Ub);
    unsigned short* Vpp = (unsigned short*)(ws + off_V);
    unsigned short* Tpp = (unsigned short*)(ws + off_T);
    float*          inv = (float*)(ws + off_inv);

    prep_kernel<<<1088, 256, 0, stream>>>(vals, U, cw, cb, S, Vpp, Ut, Ub, inv);
    gemm_kernel<1><<<512, 256, 0, stream>>>(Ut, Vpp, inv, Tpp, nullptr);
    gemm_kernel<2><<<512, 256, 0, stream>>>(Ub, Tpp, nullptr, nullptr, out);
}

// Round 13
// 36.479 us; speedup vs baseline: 3.9445x; 1.1678x over previous
//
#include <hip/hip_runtime.h>
#include <hip/hip_bf16.h>
#include <cstdint>
#include <cmath>

// Problem constants
#define LSEQ 512
#define EDIM 64
#define NBIG 8192   // 16*8*64 total n dimension

typedef __attribute__((ext_vector_type(8))) short short8;
typedef __attribute__((ext_vector_type(8))) unsigned short ushort8v;
typedef __attribute__((ext_vector_type(4))) float f32x4;

__device__ __forceinline__ unsigned short f2bf(float f) {
    union { float f; unsigned int u; } x; x.f = f;
    unsigned int r = x.u + 0x7FFFu + ((x.u >> 16) & 1u);
    return (unsigned short)(r >> 16);
}

__device__ __forceinline__ void async_copy16(void* lds, const void* g) {
    auto g1 = (const __attribute__((address_space(1))) void*)g;
    auto l3 = (__attribute__((address_space(3))) void*)lds;
    __builtin_amdgcn_global_load_lds(g1, l3, 16, 0, 0);
}

// ---------------------------------------------------------------------------
// Prep (round 13): conflict-free conv mapping + LDS-staged coalesced writes.
//  blocks 0..1023  : (b,h,jt) — values tile -> Vpp bf16 swizzled [n][j] + conv->inv
//  blocks 1024..1087: U tiles — Ut[m][j]=U[j][m], Ub[i][m]=U[i][m], swizzled
// Swizzle convention (unchanged): within each 64-elem chunk, 8-elem granule g
// stored at physical granule g ^ (row & 7).
__global__ __launch_bounds__(256) void prep_kernel(
        const float* __restrict__ vals, const float* __restrict__ U,
        const float* __restrict__ cw, const float* __restrict__ cb,
        const float* __restrict__ S,
        unsigned short* __restrict__ Vpp, unsigned short* __restrict__ Ut,
        unsigned short* __restrict__ Ub, float* __restrict__ inv) {
    __shared__ float Ls[70 * 65];                 // fp32 tile, odd stride
    __shared__ __align__(16) unsigned short Bs[64 * 72];  // bf16 staging, 144B rows
    __shared__ float cpart[4][64];
    __shared__ float wT[448];                     // wT[k*64 + e] = cw[e*7 + k]
    int id = blockIdx.x;
    int t = threadIdx.x;

    if (id < 1024) {
        int b = id >> 6, h = (id >> 3) & 7, jt = id & 7;
        int j0 = jt * 64;
        for (int idx = t; idx < 448; idx += 256) {
            int e = idx / 7, k = idx - e * 7;
            wT[k * 64 + e] = cw[idx];
        }
        // load 70 rows (j0-3 .. j0+66, clamped) x 64 cols fp32
        const float* base = vals + (size_t)b * 262144 + h * 64;
        #pragma unroll
        for (int i = 0; i < 5; ++i) {
            int idx = i * 256 + t;
            if (idx < 1120) {
                int row = idx >> 4, c4 = (idx & 15) * 4;
                int grow = j0 + row - 3;
                grow = grow < 0 ? 0 : (grow > 511 ? 511 : grow);
                float4 v = *(const float4*)(base + (size_t)grow * 512 + c4);
                float* d = &Ls[row * 65 + c4];
                d[0] = v.x; d[1] = v.y; d[2] = v.z; d[3] = v.w;
            }
        }
        __syncthreads();

        // 2a: transpose + f2bf -> Bs (swizzle baked; col-reads stride-65 = free)
        {
            int e = t & 63, q = t >> 6;
            unsigned short o[16];
            #pragma unroll
            for (int jj = 0; jj < 16; ++jj)
                o[jj] = f2bf(Ls[(3 + q * 16 + jj) * 65 + e]);
            int x = e & 7;                       // n&7 == e&7 (n base mult of 8)
            int g0 = (2 * q) ^ x, g1 = (2 * q + 1) ^ x;
            *(ushort8v*)&Bs[e * 72 + g0 * 8] = *(const ushort8v*)o;
            *(ushort8v*)&Bs[e * 72 + g1 * 8] = *(const ushort8v*)(o + 8);
        }

        // 2b: conv partials, conflict-free: l per lane (bank = l+c mod 32),
        // weights wave-uniform broadcast from wT.
        {
            int l = t & 63, eg = t >> 6;
            float a0 = 0.f, a1 = 0.f, a2 = 0.f, a3 = 0.f;
            #pragma unroll
            for (int k = 0; k < 7; ++k) {
                const float* dr = &Ls[(l + k) * 65 + eg * 16];
                const float* wr = &wT[k * 64 + eg * 16];
                #pragma unroll
                for (int j = 0; j < 4; ++j) {
                    a0 += dr[4*j + 0] * wr[4*j + 0];
                    a1 += dr[4*j + 1] * wr[4*j + 1];
                    a2 += dr[4*j + 2] * wr[4*j + 2];
                    a3 += dr[4*j + 3] * wr[4*j + 3];
                }
            }
            cpart[eg][l] = (a0 + a1) + (a2 + a3);
        }
        __syncthreads();

        // 3a: coalesced Vpp writes: 4 lanes cover one contiguous 128B row chunk
        {
            int r = t >> 2, c = (t & 3) * 16;
            int n = b * 512 + h * 64 + r;
            unsigned short* dst = Vpp + (size_t)n * 512 + j0 + c;
            *(ushort8v*)dst       = *(const ushort8v*)&Bs[r * 72 + c];
            *(ushort8v*)(dst + 8) = *(const ushort8v*)&Bs[r * 72 + c + 8];
        }
        // 3b: inv
        if (t < 64) {
            float y = cb[0] + (cpart[0][t] + cpart[1][t]) + (cpart[2][t] + cpart[3][t]);
            float lam = (y > 0.f) ? (1.f + y) : expf(y);   // 1 + elu(y)
            inv[(size_t)(b * 8 + h) * 512 + j0 + t] = 1.f / (1.f + lam * S[j0 + t]);
        }
    } else {
        // U tile: 64x64 at (j0, m0)
        int id2 = id - 1024;
        int j0 = (id2 >> 3) * 64, m0 = (id2 & 7) * 64;
        int r = t >> 2, c4 = t & 3;
        int c16 = c4 * 16;
        float v[16];
        const float* src = U + (size_t)(j0 + r) * 512 + m0 + c16;
        #pragma unroll
        for (int k = 0; k < 16; k += 4) {
            float4 vv = *(const float4*)(src + k);
            v[k] = vv.x; v[k+1] = vv.y; v[k+2] = vv.z; v[k+3] = vv.w;
        }
        // stage Ub row (j0+r, chunk m0), swizzled by x = (j0+r)&7 = r&7
        {
            unsigned short o[16];
            #pragma unroll
            for (int k = 0; k < 16; ++k) o[k] = f2bf(v[k]);
            int x = r & 7;
            int g0 = (2 * c4) ^ x, g1 = (2 * c4 + 1) ^ x;
            *(ushort8v*)&Bs[r * 72 + g0 * 8] = *(const ushort8v*)o;
            *(ushort8v*)&Bs[r * 72 + g1 * 8] = *(const ushort8v*)(o + 8);
        }
        // row-major into Ls for the transpose
        #pragma unroll
        for (int k = 0; k < 16; ++k) Ls[r * 65 + c16 + k] = v[k];
        __syncthreads();
        // copy Ub out (coalesced)
        {
            unsigned short* dst = Ub + (size_t)(j0 + r) * 512 + m0 + c16;
            *(ushort8v*)dst       = *(const ushort8v*)&Bs[r * 72 + c16];
            *(ushort8v*)(dst + 8) = *(const ushort8v*)&Bs[r * 72 + c16 + 8];
        }
        // transposed read: o[k] = U[j0+c16+k][m0+r] -> Ut row m0+r
        unsigned short o[16];
        #pragma unroll
        for (int k = 0; k < 16; ++k) o[k] = f2bf(Ls[(c16 + k) * 65 + r]);
        __syncthreads();   // Bs fully consumed before restage
        {
            int x = r & 7;                      // (m0+r)&7
            int g0 = (2 * c4) ^ x, g1 = (2 * c4 + 1) ^ x;
            *(ushort8v*)&Bs[r * 72 + g0 * 8] = *(const ushort8v*)o;
            *(ushort8v*)&Bs[r * 72 + g1 * 8] = *(const ushort8v*)(o + 8);
        }
        __syncthreads();
        {
            unsigned short* dst = Ut + (size_t)(m0 + r) * 512 + j0 + c16;
            *(ushort8v*)dst       = *(const ushort8v*)&Bs[r * 72 + c16];
            *(ushort8v*)(dst + 8) = *(const ushort8v*)&Bs[r * 72 + c16 + 8];
        }
    }
}

// ---------------------------------------------------------------------------
// GEMM (round-6 config verbatim): C[512][8192] = A[512x512] * B[n][k],
// tile 128m x 64n, BK=64, double-buffered; 512 blocks, 2/CU independent.
// EPI=1: Tpp[n][m] = bf16(C * inv), swizzled.  EPI=2: out fp32.
template<int EPI>
__launch_bounds__(256, 2)
__global__ void gemm_kernel(const unsigned short* __restrict__ A,
                            const unsigned short* __restrict__ B,
                            const float* __restrict__ inv,
                            unsigned short* __restrict__ Tout,
                            float* __restrict__ Out) {
    __shared__ __align__(16) unsigned short As[2][128 * 64];
    __shared__ __align__(16) unsigned short Bs[2][64 * 64];

    int bid = blockIdx.x;
    bid = (bid & 7) * 64 + (bid >> 3);           // XCD chunked swizzle (512 % 8 == 0)
    int mt = bid & 3, nt = bid >> 2;
    int m0 = mt * 128, n0 = nt * 64;
    int t = threadIdx.x, lane = t & 63, wave = t >> 6;
    int wm = wave >> 1, wn = wave & 1;
    int l15 = lane & 15, l4 = lane >> 4;

    f32x4 acc[4][2] = {};

    const unsigned short* Ab = A + (size_t)(m0 + (t >> 3)) * 512 + (t & 7) * 8;
    const unsigned short* Bb = B + (size_t)(n0 + (t >> 3)) * 512 + (t & 7) * 8;

    auto STAGE = [&](int buf, int kk) {
        int ko = kk * 64;
        unsigned short* ap = &As[buf][t * 8];
        unsigned short* bp = &Bs[buf][t * 8];
        async_copy16(ap,        Ab + ko);
        async_copy16(ap + 2048, Ab + (size_t)32 * 512 + ko);
        async_copy16(ap + 4096, Ab + (size_t)64 * 512 + ko);
        async_copy16(ap + 6144, Ab + (size_t)96 * 512 + ko);
        async_copy16(bp,        Bb + ko);
        async_copy16(bp + 2048, Bb + (size_t)32 * 512 + ko);
    };
    auto COMPUTE = [&](int buf) {
        #pragma unroll
        for (int k2 = 0; k2 < 2; ++k2) {
            short8 a[4], bf[2];
            #pragma unroll
            for (int i = 0; i < 4; ++i) {
                int row = wm * 64 + i * 16 + l15;
                a[i] = *(const short8*)&As[buf][row * 64 + (((k2 * 4 + l4) ^ (row & 7)) << 3)];
            }
            #pragma unroll
            for (int j = 0; j < 2; ++j) {
                int row = wn * 32 + j * 16 + l15;
                bf[j] = *(const short8*)&Bs[buf][row * 64 + (((k2 * 4 + l4) ^ (row & 7)) << 3)];
            }
            #pragma unroll
            for (int i = 0; i < 4; ++i)
                #pragma unroll
                for (int j = 0; j < 2; ++j)
                    acc[i][j] = __builtin_amdgcn_mfma_f32_16x16x32_bf16(a[i], bf[j], acc[i][j], 0, 0, 0);
        }
    };

    STAGE(0, 0);
    __syncthreads();
    int cur = 0;
    #pragma unroll
    for (int kk = 0; kk < 7; ++kk) {
        STAGE(cur ^ 1, kk + 1);
        COMPUTE(cur);
        __syncthreads();
        cur ^= 1;
    }
    COMPUTE(cur);

    #pragma unroll
    for (int i = 0; i < 4; ++i) {
        int mb = m0 + wm * 64 + i * 16 + l4 * 4;
        if (EPI == 1) {
            float4 s = *(const float4*)&inv[(size_t)nt * 512 + mb];
            #pragma unroll
            for (int j = 0; j < 2; ++j) {
                int n = n0 + wn * 32 + j * 16 + l15;
                f32x4 v = acc[i][j];
                ushort4 pack;
                pack.x = f2bf(v[0] * s.x);
                pack.y = f2bf(v[1] * s.y);
                pack.z = f2bf(v[2] * s.z);
                pack.w = f2bf(v[3] * s.w);
                int e = mb & 63;
                int pos = (mb & ~63) + ((((e >> 3) ^ (n & 7)) << 3) | (e & 7));
                *(ushort4*)&Tout[(size_t)n * 512 + pos] = pack;
            }
        } else {
            #pragma unroll
            for (int j = 0; j < 2; ++j) {
                int n = n0 + wn * 32 + j * 16 + l15;
                int b = n >> 9, hd = n & 511;
                f32x4 v = acc[i][j];
                float* o = Out + (size_t)b * 262144 + (size_t)mb * 512 + hd;
                o[0] = v[0]; o[512] = v[1]; o[1024] = v[2]; o[1536] = v[3];
            }
        }
    }
}

// ---------------------------------------------------------------------------
extern "C" void kernel_launch(void* const* d_in, const int* in_sizes, int n_in,
                              void* d_out, int out_size, void* d_ws, size_t ws_size,
                              hipStream_t stream) {
    const float* vals = (const float*)d_in[0];
    const float* cw   = (const float*)d_in[1];
    const float* cb   = (const float*)d_in[2];
    const float* U    = (const float*)d_in[3];
    const float* S    = (const float*)d_in[4];
    float* out = (float*)d_out;

    const size_t off_Ut  = 0;              // 512KB
    const size_t off_Ub  = 524288;         // 512KB
    const size_t off_V   = 1048576;        // 8MB
    const size_t off_T   = 9437184;        // 8MB
    const size_t off_inv = 17825792;       // 256KB
    const size_t ws_need = 18087936;
    if (ws_size < ws_need) return;

    char* ws = (char*)d_ws;
    unsigned short* Ut  = (unsigned short*)(ws + off_Ut);
    unsigned short* Ub  = (unsigned short*)(ws + off_Ub);
    unsigned short* Vpp = (unsigned short*)(ws + off_V);
    unsigned short* Tpp = (unsigned short*)(ws + off_T);
    float*          inv = (float*)(ws + off_inv);

    prep_kernel<<<1088, 256, 0, stream>>>(vals, U, cw, cb, S, Vpp, Ut, Ub, inv);
    gemm_kernel<1><<<512, 256, 0, stream>>>(Ut, Vpp, inv, Tpp, nullptr);
    gemm_kernel<2><<<512, 256, 0, stream>>>(Ub, Tpp, nullptr, nullptr, out);
}

// Round 14
// 34.672 us; speedup vs baseline: 4.1501x; 1.0521x over previous
//
#include <hip/hip_runtime.h>
#include <hip/hip_bf16.h>
#include <cstdint>
#include <cmath>

// Problem constants
#define LSEQ 512
#define EDIM 64
#define NBIG 8192   // 16*8*64 total n dimension

typedef __attribute__((ext_vector_type(8))) short short8;
typedef __attribute__((ext_vector_type(8))) unsigned short ushort8v;
typedef __attribute__((ext_vector_type(4))) float f32x4;

__device__ __forceinline__ unsigned short f2bf(float f) {
    union { float f; unsigned int u; } x; x.f = f;
    unsigned int r = x.u + 0x7FFFu + ((x.u >> 16) & 1u);
    return (unsigned short)(r >> 16);
}

__device__ __forceinline__ void async_copy16(void* lds, const void* g) {
    auto g1 = (const __attribute__((address_space(1))) void*)g;
    auto l3 = (__attribute__((address_space(3))) void*)lds;
    __builtin_amdgcn_global_load_lds(g1, l3, 16, 0, 0);
}

// Swizzled 16-elem store: within the 64-elem chunk at cbase, 8-elem granule g
// lands at physical granule p = g ^ (row & 7).
__device__ __forceinline__ void store16_swz(unsigned short* rowptr, int cbase,
                                            int q, int row,
                                            const unsigned short* o) {
    int x = row & 7, x1 = x >> 1, x0 = x & 1;
    unsigned short* dst = rowptr + cbase + ((q ^ x1) << 4);
    ushort8v lo = *(const ushort8v*)o;
    ushort8v hi = *(const ushort8v*)(o + 8);
    if (x0) { *(ushort8v*)dst = hi; *(ushort8v*)(dst + 8) = lo; }
    else    { *(ushort8v*)dst = lo; *(ushort8v*)(dst + 8) = hi; }
}

// ---------------------------------------------------------------------------
// Fused prep (round-6 version):
//  blocks 0..1023  : (b,h,jt) — stage values tile, emit Vpp bf16 swizzled [n][j]
//                    (n=b*512+h*64+e), plus conv->lambda->inv
//  blocks 1024..1087: U tiles — emit Ut[m][j]=U[j][m], Ub[i][m]=U[i][m], swizzled
__global__ __launch_bounds__(256) void prep_kernel(
        const float* __restrict__ vals, const float* __restrict__ U,
        const float* __restrict__ cw, const float* __restrict__ cb,
        const float* __restrict__ S,
        unsigned short* __restrict__ Vpp, unsigned short* __restrict__ Ut,
        unsigned short* __restrict__ Ub, float* __restrict__ inv) {
    __shared__ float Ls[70 * 65];        // stride 65 (odd) -> conflict-free both axes
    __shared__ float red[16][64];
    __shared__ float wcoef[448];
    int id = blockIdx.x;
    int t = threadIdx.x;

    if (id < 1024) {
        int b = id >> 6, h = (id >> 3) & 7, jt = id & 7;
        int j0 = jt * 64;
        // 256-thread block: strided fill of all 448 weights.
        for (int idx = t; idx < 448; idx += 256) wcoef[idx] = cw[idx];
        // load 70 rows (j0-3 .. j0+66, clamped) x 64 cols fp32
        const float* base = vals + (size_t)b * 262144 + h * 64;
        #pragma unroll
        for (int i = 0; i < 5; ++i) {
            int idx = i * 256 + t;
            if (idx < 1120) {
                int row = idx >> 4, c4 = (idx & 15) * 4;
                int grow = j0 + row - 3;
                grow = grow < 0 ? 0 : (grow > 511 ? 511 : grow);
                float4 v = *(const float4*)(base + (size_t)grow * 512 + c4);
                float* d = &Ls[row * 65 + c4];
                d[0] = v.x; d[1] = v.y; d[2] = v.z; d[3] = v.w;
            }
        }
        __syncthreads();

        // transpose -> Vpp (bf16, swizzled). thread: e = t&63, q = t>>6
        {
            int e = t & 63, q = t >> 6;
            unsigned short o[16];
            #pragma unroll
            for (int jj = 0; jj < 16; ++jj)
                o[jj] = f2bf(Ls[(3 + q * 16 + jj) * 65 + e]);
            int n = b * 512 + h * 64 + e;
            store16_swz(Vpp + (size_t)n * 512, j0, q, n, o);
        }

        // conv partials: thread: lg = t&15 (4 l's), q16 = t>>4 (4 e's)
        {
            int lg = t & 15, q16 = t >> 4;
            int l0 = lg * 4, e0 = q16 * 4;
            float rv[10][4];
            #pragma unroll
            for (int r = 0; r < 10; ++r)
                #pragma unroll
                for (int je = 0; je < 4; ++je)
                    rv[r][je] = Ls[(l0 + r) * 65 + e0 + je];
            float a4[4] = {0.f, 0.f, 0.f, 0.f};
            #pragma unroll
            for (int kk = 0; kk < 7; ++kk) {
                #pragma unroll
                for (int je = 0; je < 4; ++je) {
                    float w = wcoef[(e0 + je) * 7 + kk];
                    #pragma unroll
                    for (int dl = 0; dl < 4; ++dl)
                        a4[dl] += rv[dl + kk][je] * w;
                }
            }
            #pragma unroll
            for (int dl = 0; dl < 4; ++dl) red[q16][l0 + dl] = a4[dl];
        }
        __syncthreads();
        if (t < 64) {
            float y = cb[0];
            #pragma unroll
            for (int g = 0; g < 16; ++g) y += red[g][t];
            float lam = (y > 0.f) ? (1.f + y) : expf(y);   // 1 + elu(y)
            inv[(size_t)(b * 8 + h) * 512 + j0 + t] = 1.f / (1.f + lam * S[j0 + t]);
        }
    } else {
        int id2 = id - 1024;
        int j0 = (id2 >> 3) * 64, m0 = (id2 & 7) * 64;
        int r = t >> 2, q = t & 3;
        int c16 = q * 16;
        float v[16];
        const float* src = U + (size_t)(j0 + r) * 512 + m0 + c16;
        #pragma unroll
        for (int k = 0; k < 16; k += 4) {
            float4 vv = *(const float4*)(src + k);
            v[k] = vv.x; v[k+1] = vv.y; v[k+2] = vv.z; v[k+3] = vv.w;
        }
        // straight copy -> Ub (row j0+r, chunk m0), swizzled
        {
            unsigned short o[16];
            #pragma unroll
            for (int k = 0; k < 16; ++k) o[k] = f2bf(v[k]);
            store16_swz(Ub + (size_t)(j0 + r) * 512, m0, q, j0 + r, o);
        }
        // row-major into LDS: Ls[j_local][m_local]
        #pragma unroll
        for (int k = 0; k < 16; ++k) Ls[r * 65 + c16 + k] = v[k];
        __syncthreads();
        // transposed read: o[k] = U[j0+c16+k][m0+r]  -> Ut[m0+r][j0+c16+k]
        {
            unsigned short o[16];
            #pragma unroll
            for (int k = 0; k < 16; ++k) o[k] = f2bf(Ls[(c16 + k) * 65 + r]);
            store16_swz(Ut + (size_t)(m0 + r) * 512, j0, q, m0 + r, o);
        }
    }
}

// ---------------------------------------------------------------------------
// GEMM (round-6 config): C[512][8192] = A[512x512] * B[n][k] (both bf16,
// granule-swizzled rows), tile 128m x 64n, BK=64, double-buffered;
// 512 blocks, 2/CU independent.
// EPI=1: Tpp[n][m] = bf16(C * inv), swizzled.  EPI=2: out fp32.
template<int EPI>
__launch_bounds__(256, 2)
__global__ void gemm_kernel(const unsigned short* __restrict__ A,
                            const unsigned short* __restrict__ B,
                            const float* __restrict__ inv,
                            unsigned short* __restrict__ Tout,
                            float* __restrict__ Out) {
    __shared__ __align__(16) unsigned short As[2][128 * 64];
    __shared__ __align__(16) unsigned short Bs[2][64 * 64];

    int bid = blockIdx.x;
    bid = (bid & 7) * 64 + (bid >> 3);           // XCD chunked swizzle (512 % 8 == 0)
    int mt = bid & 3, nt = bid >> 2;
    int m0 = mt * 128, n0 = nt * 64;
    int t = threadIdx.x, lane = t & 63, wave = t >> 6;
    int wm = wave >> 1, wn = wave & 1;
    int l15 = lane & 15, l4 = lane >> 4;

    f32x4 acc[4][2] = {};

    const unsigned short* Ab = A + (size_t)(m0 + (t >> 3)) * 512 + (t & 7) * 8;
    const unsigned short* Bb = B + (size_t)(n0 + (t >> 3)) * 512 + (t & 7) * 8;

    auto STAGE = [&](int buf, int kk) {
        int ko = kk * 64;
        unsigned short* ap = &As[buf][t * 8];
        unsigned short* bp = &Bs[buf][t * 8];
        async_copy16(ap,        Ab + ko);
        async_copy16(ap + 2048, Ab + (size_t)32 * 512 + ko);
        async_copy16(ap + 4096, Ab + (size_t)64 * 512 + ko);
        async_copy16(ap + 6144, Ab + (size_t)96 * 512 + ko);
        async_copy16(bp,        Bb + ko);
        async_copy16(bp + 2048, Bb + (size_t)32 * 512 + ko);
    };
    auto COMPUTE = [&](int buf) {
        #pragma unroll
        for (int k2 = 0; k2 < 2; ++k2) {
            short8 a[4], bf[2];
            #pragma unroll
            for (int i = 0; i < 4; ++i) {
                int row = wm * 64 + i * 16 + l15;
                a[i] = *(const short8*)&As[buf][row * 64 + (((k2 * 4 + l4) ^ (row & 7)) << 3)];
            }
            #pragma unroll
            for (int j = 0; j < 2; ++j) {
                int row = wn * 32 + j * 16 + l15;
                bf[j] = *(const short8*)&Bs[buf][row * 64 + (((k2 * 4 + l4) ^ (row & 7)) << 3)];
            }
            #pragma unroll
            for (int i = 0; i < 4; ++i)
                #pragma unroll
                for (int j = 0; j < 2; ++j)
                    acc[i][j] = __builtin_amdgcn_mfma_f32_16x16x32_bf16(a[i], bf[j], acc[i][j], 0, 0, 0);
        }
    };

    STAGE(0, 0);
    __syncthreads();
    int cur = 0;
    #pragma unroll
    for (int kk = 0; kk < 7; ++kk) {
        STAGE(cur ^ 1, kk + 1);
        COMPUTE(cur);
        __syncthreads();
        cur ^= 1;
    }
    COMPUTE(cur);

    #pragma unroll
    for (int i = 0; i < 4; ++i) {
        int mb = m0 + wm * 64 + i * 16 + l4 * 4;
        if (EPI == 1) {
            float4 s = *(const float4*)&inv[(size_t)nt * 512 + mb];
            #pragma unroll
            for (int j = 0; j < 2; ++j) {
                int n = n0 + wn * 32 + j * 16 + l15;
                f32x4 v = acc[i][j];
                ushort4 pack;
                pack.x = f2bf(v[0] * s.x);
                pack.y = f2bf(v[1] * s.y);
                pack.z = f2bf(v[2] * s.z);
                pack.w = f2bf(v[3] * s.w);
                int e = mb & 63;
                int pos = (mb & ~63) + ((((e >> 3) ^ (n & 7)) << 3) | (e & 7));
                *(ushort4*)&Tout[(size_t)n * 512 + pos] = pack;
            }
        } else {
            #pragma unroll
            for (int j = 0; j < 2; ++j) {
                int n = n0 + wn * 32 + j * 16 + l15;
                int b = n >> 9, hd = n & 511;
                f32x4 v = acc[i][j];
                float* o = Out + (size_t)b * 262144 + (size_t)mb * 512 + hd;
                o[0] = v[0]; o[512] = v[1]; o[1024] = v[2]; o[1536] = v[3];
            }
        }
    }
}

// ---------------------------------------------------------------------------
extern "C" void kernel_launch(void* const* d_in, const int* in_sizes, int n_in,
                              void* d_out, int out_size, void* d_ws, size_t ws_size,
                              hipStream_t stream) {
    const float* vals = (const float*)d_in[0];
    const float* cw   = (const float*)d_in[1];
    const float* cb   = (const float*)d_in[2];
    const float* U    = (const float*)d_in[3];
    const float* S    = (const float*)d_in[4];
    float* out = (float*)d_out;

    const size_t off_Ut  = 0;              // 512KB
    const size_t off_Ub  = 524288;         // 512KB
    const size_t off_V   = 1048576;        // 8MB
    const size_t off_T   = 9437184;        // 8MB
    const size_t off_inv = 17825792;       // 256KB
    const size_t ws_need = 18087936;
    if (ws_size < ws_need) return;

    char* ws = (char*)d_ws;
    unsigned short* Ut  = (unsigned short*)(ws + off_Ut);
    unsigned short* Ub  = (unsigned short*)(ws + off_Ub);
    unsigned short* Vpp = (unsigned short*)(ws + off_V);
    unsigned short* Tpp = (unsigned short*)(ws + off_T);
    float*          inv = (float*)(ws + off_inv);

    prep_kernel<<<1088, 256, 0, stream>>>(vals, U, cw, cb, S, Vpp, Ut, Ub, inv);
    gemm_kernel<1><<<512, 256, 0, stream>>>(Ut, Vpp, inv, Tpp, nullptr);
    gemm_kernel<2><<<512, 256, 0, stream>>>(Ub, Tpp, nullptr, nullptr, out);
}